// Round 16
// baseline (270.388 us; speedup 1.0000x reference)
//
#include <hip/hip_runtime.h>
#include <hip/hip_fp16.h>
#include <math.h>

#define NN 100000
#define NE 1600000
#define NF 128
#define NH 64
#define NBUCK 196     // ceil(NN / 512)
#define CHA 8192      // edges per block in partition pass
#define CAP 10240     // per-bucket capacity (mean 8163, +23 sigma)
#define NBLK 1563     // ceil(NN / 64) for MFMA GEMMs

typedef _Float16 f16x8 __attribute__((ext_vector_type(8)));
typedef float f32x4 __attribute__((ext_vector_type(4)));

// Pass A: partition edges into 512-node dst-buckets (fixed-capacity regions).
// dst chunk cached in LDS; per-wave histograms cut LDS-atomic contention 4x.
__global__ __launch_bounds__(256) void part_bucket2(const int* __restrict__ src,
                                                    const int* __restrict__ dst,
                                                    int* __restrict__ bcnt,
                                                    int* __restrict__ tmp, int E) {
    __shared__ int hist[4][NBUCK];
    __shared__ int wbase[4][NBUCK];
    __shared__ int dbuf[CHA];    // 32 KB
    int t = threadIdx.x;
    int w = t >> 6;
    int e0 = blockIdx.x * CHA;
    int n = min(CHA, E - e0);
    for (int i = t; i < 4 * NBUCK; i += 256) ((int*)hist)[i] = 0;
    __syncthreads();
    for (int i = t; i < n; i += 256) {
        int d = dst[e0 + i];
        dbuf[i] = d;
        atomicAdd(&hist[w][d >> 9], 1);
    }
    __syncthreads();
    if (t < NBUCK) {
        int h0 = hist[0][t], h1 = hist[1][t], h2 = hist[2][t], h3 = hist[3][t];
        int tot = h0 + h1 + h2 + h3;
        int base = tot ? atomicAdd(&bcnt[t], tot) : 0;
        wbase[0][t] = base;
        wbase[1][t] = base + h0;
        wbase[2][t] = base + h0 + h1;
        wbase[3][t] = base + h0 + h1 + h2;
    }
    __syncthreads();
    for (int i = t; i < 4 * NBUCK; i += 256) ((int*)hist)[i] = 0;
    __syncthreads();
    for (int i = t; i < n; i += 256) {
        int d = dbuf[i];
        int b = d >> 9;
        int r = atomicAdd(&hist[w][b], 1);
        tmp[b * CAP + wbase[w][b] + r] = ((d & 511) << 17) | src[e0 + i];
    }
}

// Pass B: one block per bucket. Re-derives its CSR base from bcnt (local scan),
// stages entries in LDS, per-node degree histogram (-> rowptr, dsq), LDS scan,
// LDS-cursor scatter into csr_src.
__global__ __launch_bounds__(256) void bucket_finalize(const int* __restrict__ bcnt,
                                                       const int* __restrict__ tmp,
                                                       int* __restrict__ rowptr,
                                                       float* __restrict__ dsq,
                                                       int* __restrict__ csr_src) {
    __shared__ int ebuf[CAP];   // 40 KB
    __shared__ int hcnt[512];
    __shared__ int hoff[512];
    __shared__ int s[256];
    int b = blockIdx.x, t = threadIdx.x;

    // local exclusive scan of bcnt -> this bucket's CSR base
    s[t] = (t < NBUCK) ? bcnt[t] : 0;
    __syncthreads();
    for (int off = 1; off < 256; off <<= 1) {
        int v = (t >= off) ? s[t - off] : 0;
        __syncthreads();
        s[t] += v;
        __syncthreads();
    }
    int base = (b == 0) ? 0 : s[b - 1];
    int cb = bcnt[b];
    if (b == 0 && t == 0) rowptr[NN] = NE;
    __syncthreads();

    const int* tsrc = tmp + b * CAP;
    for (int i = t; i < cb; i += 256) ebuf[i] = tsrc[i];
    hcnt[t] = 0;
    hcnt[t + 256] = 0;
    __syncthreads();
    for (int i = t; i < cb; i += 256) atomicAdd(&hcnt[ebuf[i] >> 17], 1);
    __syncthreads();
    int c0 = hcnt[2 * t], c1 = hcnt[2 * t + 1];
    s[t] = c0 + c1;
    __syncthreads();
    for (int off = 1; off < 256; off <<= 1) {
        int v = (t >= off) ? s[t - off] : 0;
        __syncthreads();
        s[t] += v;
        __syncthreads();
    }
    int pb = (t == 0) ? 0 : s[t - 1];
    hoff[2 * t] = pb;
    hoff[2 * t + 1] = pb + c0;
    __syncthreads();
    int nodelo = b << 9;
    int nnodes = min(512, NN - nodelo);
    for (int i = t; i < nnodes; i += 256) {
        rowptr[nodelo + i] = base + hoff[i];
        dsq[nodelo + i] = rsqrtf((float)hcnt[i] + 1.0f);
    }
    __syncthreads();
    for (int i = t; i < cb; i += 256) {
        int e = ebuf[i];
        int dlow = e >> 17;
        int p = atomicAdd(&hoff[dlow], 1);
        csr_src[base + p] = e & 0x1FFFF;
    }
}

// merged weight prep. blocks 0-31: Wct=(We@W0)^T fp16 + bc; 32-47: Wt1; 48-63: Wt2.
__global__ __launch_bounds__(256) void prep_w(const float* __restrict__ We,
                                              const float* __restrict__ be,
                                              const float* __restrict__ Ws,
                                              _Float16* __restrict__ Wct,
                                              float* __restrict__ bc,
                                              _Float16* __restrict__ Wt1,
                                              _Float16* __restrict__ Wt2) {
    int bb = blockIdx.x;
    int t = threadIdx.x;
    if (bb < 32) {
        __shared__ float w0[NH * NH];
        for (int i = t; i < NH * NH; i += 256) w0[i] = Ws[i];
        __syncthreads();
        int row = bb * 4 + (t >> 6);  // k index 0..127
        int col = t & 63;
        float a = 0.f;
#pragma unroll 8
        for (int k = 0; k < NH; ++k) a += We[row * NH + k] * w0[k * NH + col];
        Wct[col * NF + row] = (_Float16)a;
        if (bb == 0 && t < NH) {
            float s = 0.f;
            for (int k = 0; k < NH; ++k) s += be[k] * w0[k * NH + t];
            bc[t] = s;
        }
    } else {
        int which = (bb - 32) >> 4;          // 0 -> Wt1, 1 -> Wt2
        int i = ((bb - 32) & 15) * 256 + t;  // 0..4095
        int k = i >> 6, c = i & 63;
        const float* W = Ws + (which + 1) * NH * NH;
        _Float16* Wt = which ? Wt2 : Wt1;
        Wt[c * NH + k] = (_Float16)W[i];
    }
}

// hws0 = (x @ Wc + bc) * dsq[row], fp16 out. MFMA 16x16x32_f16, 64 rows/block.
__global__ __launch_bounds__(256) void fuse0_gemm(const float* __restrict__ x,
                                                  const _Float16* __restrict__ Wct,
                                                  const float* __restrict__ bc,
                                                  const float* __restrict__ dsq,
                                                  __half* __restrict__ hws) {
    __shared__ _Float16 sh[64 * NF];  // 16 KB, 256B rows, XOR-swizzled
    int t = threadIdx.x;
    int lane = t & 63;
    int w = t >> 6;
    int row0 = blockIdx.x * 64;

    f16x8 bf[4][4];
#pragma unroll
    for (int ct = 0; ct < 4; ++ct)
#pragma unroll
        for (int ks = 0; ks < 4; ++ks) {
            int col = ct * 16 + (lane & 15);
            int k = ks * 32 + (lane >> 4) * 8;
            bf[ct][ks] = *(const f16x8*)(Wct + col * NF + k);
        }

    const float4* xs = (const float4*)x;
#pragma unroll
    for (int i = 0; i < 8; ++i) {
        int f = t + i * 256;
        int r = f >> 5;
        int c4 = f & 31;
        int row = min(row0 + r, NN - 1);
        float4 v = xs[(size_t)row * 32 + c4];
        __half2 h0 = __floats2half2_rn(v.x, v.y);
        __half2 h1 = __floats2half2_rn(v.z, v.w);
        uint2 u;
        u.x = *(unsigned*)&h0;
        u.y = *(unsigned*)&h1;
        int byte = (r * 256 + c4 * 8) ^ ((r & 7) << 4);
        *(uint2*)((char*)sh + byte) = u;
    }
    __syncthreads();

    f32x4 acc[4] = {{0.f, 0.f, 0.f, 0.f}, {0.f, 0.f, 0.f, 0.f},
                    {0.f, 0.f, 0.f, 0.f}, {0.f, 0.f, 0.f, 0.f}};
    int ar = w * 16 + (lane & 15);
    int ak = (lane >> 4) * 8;
#pragma unroll
    for (int ks = 0; ks < 4; ++ks) {
        int byte = (ar * 256 + (ks * 32 + ak) * 2) ^ ((ar & 7) << 4);
        f16x8 af = *(const f16x8*)((const char*)sh + byte);
#pragma unroll
        for (int ct = 0; ct < 4; ++ct)
            acc[ct] = __builtin_amdgcn_mfma_f32_16x16x32_f16(af, bf[ct][ks], acc[ct], 0, 0, 0);
    }
#pragma unroll
    for (int ct = 0; ct < 4; ++ct) {
        int col = ct * 16 + (lane & 15);
        float bcv = bc[col];
#pragma unroll
        for (int r2 = 0; r2 < 4; ++r2) {
            int row = row0 + w * 16 + (lane >> 4) * 4 + r2;
            if (row < NN)
                hws[(size_t)row * NH + col] = __float2half((acc[ct][r2] + bcv) * dsq[row]);
        }
    }
}

// hws = (h @ W) * dsq[row], fp16 in/out. MFMA, K=64, 64 rows/block.
__global__ __launch_bounds__(256) void layer_gemm(const __half* __restrict__ h,
                                                  const _Float16* __restrict__ Wt,
                                                  const float* __restrict__ dsq,
                                                  __half* __restrict__ hws) {
    __shared__ _Float16 sh[64 * NH];  // 8 KB, 128B rows, XOR-swizzled
    int t = threadIdx.x;
    int lane = t & 63;
    int w = t >> 6;
    int row0 = blockIdx.x * 64;

    f16x8 bf[4][2];
#pragma unroll
    for (int ct = 0; ct < 4; ++ct)
#pragma unroll
        for (int ks = 0; ks < 2; ++ks) {
            int col = ct * 16 + (lane & 15);
            int k = ks * 32 + (lane >> 4) * 8;
            bf[ct][ks] = *(const f16x8*)(Wt + col * NH + k);
        }

#pragma unroll
    for (int i = 0; i < 2; ++i) {
        int u = t + i * 256;
        int r = u >> 3;
        int c8 = u & 7;
        int row = min(row0 + r, NN - 1);
        uint4 v = *(const uint4*)(h + (size_t)row * NH + c8 * 8);
        int byte = (r * 128 + c8 * 16) ^ ((r & 7) << 4);
        *(uint4*)((char*)sh + byte) = v;
    }
    __syncthreads();

    f32x4 acc[4] = {{0.f, 0.f, 0.f, 0.f}, {0.f, 0.f, 0.f, 0.f},
                    {0.f, 0.f, 0.f, 0.f}, {0.f, 0.f, 0.f, 0.f}};
    int ar = w * 16 + (lane & 15);
    int ak = (lane >> 4) * 8;
#pragma unroll
    for (int ks = 0; ks < 2; ++ks) {
        int byte = (ar * 128 + (ks * 32 + ak) * 2) ^ ((ar & 7) << 4);
        f16x8 af = *(const f16x8*)((const char*)sh + byte);
#pragma unroll
        for (int ct = 0; ct < 4; ++ct)
            acc[ct] = __builtin_amdgcn_mfma_f32_16x16x32_f16(af, bf[ct][ks], acc[ct], 0, 0, 0);
    }
#pragma unroll
    for (int ct = 0; ct < 4; ++ct) {
        int col = ct * 16 + (lane & 15);
#pragma unroll
        for (int r2 = 0; r2 < 4; ++r2) {
            int row = row0 + w * 16 + (lane >> 4) * 4 + r2;
            if (row < NN)
                hws[(size_t)row * NH + col] = __float2half(acc[ct][r2] * dsq[row]);
        }
    }
}

// Gather core: wave per node, 4 groups of 16 lanes (4 feats/lane, 8B loads).
// Full super-steps unconditional; partial step: shfl is UNCONDITIONAL (all
// lanes, clamped index) and only the load+add is exec-masked -> no phantom
// loads, no shfl-under-divergence (R14 lesson). Numerically == R13 gather.
#define ADDROW(sidx)                                                         \
    {                                                                        \
        uint2 rv = *(const uint2*)(hws_in + (size_t)(sidx) * NH + fl);       \
        float2 f0 = __half22float2(*(const __half2*)&rv.x);                  \
        float2 f1 = __half22float2(*(const __half2*)&rv.y);                  \
        a0 += f0.x; a1 += f0.y; a2 += f1.x; a3 += f1.y;                      \
    }

#define GATHER_CHUNK(idxv, cnt)                                              \
    {                                                                        \
        int nfull = (cnt) >> 4;                                              \
        for (int sup = 0; sup < nfull; ++sup) {                              \
            int eb = sup * 16 + g;                                           \
            _Pragma("unroll")                                                \
            for (int q = 0; q < 4; ++q) {                                    \
                int s_ = __shfl((idxv), eb + q * 4);                         \
                ADDROW(s_);                                                  \
            }                                                                \
        }                                                                    \
        int ebp = (nfull << 4) + g;                                          \
        _Pragma("unroll")                                                    \
        for (int q = 0; q < 4; ++q) {                                        \
            int e = ebp + q * 4;                                             \
            int s_ = __shfl((idxv), min(e, (cnt) - 1)); /* all lanes */      \
            if (e < (cnt)) ADDROW(s_);                                       \
        }                                                                    \
    }

#define GATHER_BODY                                                          \
    int t = threadIdx.x;                                                     \
    int node = blockIdx.x * 4 + (t >> 6);                                    \
    int lane = t & 63;                                                       \
    int g = lane >> 4;            /* edge slot 0..3 */                       \
    int fl = (lane & 15) << 2;    /* feature base, 4 feats */                \
    int beg = rowptr[node], end = rowptr[node + 1];                          \
    int deg = end - beg;                                                     \
    float a0 = 0.f, a1 = 0.f, a2 = 0.f, a3 = 0.f;                            \
    if (g == 0) ADDROW(node);                                                \
    int idxl = csr_src[min(beg + lane, NE - 1)];                             \
    int degc = min(deg, 64);                                                 \
    GATHER_CHUNK(idxl, degc)                                                 \
    for (int jb = beg + 64; jb < end; jb += 64) {  /* deg>64 fallback */     \
        int remc = min(end - jb, 64);                                        \
        int idx2 = csr_src[min(jb + lane, NE - 1)];                          \
        GATHER_CHUNK(idx2, remc)                                             \
    }                                                                        \
    a0 += __shfl_xor(a0, 16); a1 += __shfl_xor(a1, 16);                      \
    a2 += __shfl_xor(a2, 16); a3 += __shfl_xor(a3, 16);                      \
    a0 += __shfl_xor(a0, 32); a1 += __shfl_xor(a1, 32);                      \
    a2 += __shfl_xor(a2, 32); a3 += __shfl_xor(a3, 32);

// h = relu(dsq*(agg+self)+b), fp16 out (feeds layer_gemm)
__global__ __launch_bounds__(256) void gather_h(const int* __restrict__ rowptr,
                                                const int* __restrict__ csr_src,
                                                const __half* __restrict__ hws_in,
                                                const float* __restrict__ dsq,
                                                const float* __restrict__ b,
                                                __half* __restrict__ hout) {
    GATHER_BODY
    if (lane < 16) {
        float ds = dsq[node];
        float4 b0 = *(const float4*)(b + fl);
        __half2 o0 = __floats2half2_rn(fmaxf(ds * a0 + b0.x, 0.f),
                                       fmaxf(ds * a1 + b0.y, 0.f));
        __half2 o1 = __floats2half2_rn(fmaxf(ds * a2 + b0.z, 0.f),
                                       fmaxf(ds * a3 + b0.w, 0.f));
        uint2 u;
        u.x = *(unsigned*)&o0;
        u.y = *(unsigned*)&o1;
        *(uint2*)(hout + (size_t)node * NH + fl) = u;
    }
}

// final: out = relu(dsq*(agg+self)+b), fp32
__global__ __launch_bounds__(256) void gather_out(const int* __restrict__ rowptr,
                                                  const int* __restrict__ csr_src,
                                                  const __half* __restrict__ hws_in,
                                                  const float* __restrict__ dsq,
                                                  const float* __restrict__ b,
                                                  float* __restrict__ outbuf) {
    GATHER_BODY
    if (lane < 16) {
        float ds = dsq[node];
        float4 b0 = *(const float4*)(b + fl);
        float4 o;
        o.x = fmaxf(ds * a0 + b0.x, 0.f);
        o.y = fmaxf(ds * a1 + b0.y, 0.f);
        o.z = fmaxf(ds * a2 + b0.z, 0.f);
        o.w = fmaxf(ds * a3 + b0.w, 0.f);
        *(float4*)(outbuf + (size_t)node * NH + fl) = o;
    }
}

extern "C" void kernel_launch(void* const* d_in, const int* in_sizes, int n_in,
                              void* d_out, int out_size, void* d_ws, size_t ws_size,
                              hipStream_t stream) {
    const float* x     = (const float*)d_in[0];
    const int*   ei    = (const int*)d_in[1];
    const float* W_emb = (const float*)d_in[2];
    const float* b_emb = (const float*)d_in[3];
    const float* Ws    = (const float*)d_in[4];
    const float* bs    = (const float*)d_in[5];
    float* out = (float*)d_out;

    const int* src = ei;
    const int* dst = ei + NE;

    char* w = (char*)d_ws;
    int*      bcnt    = (int*)w;              w += 256 * 4;
    int*      rowptr  = (int*)w;              w += (NN + 1) * 4;
    float*    dsq     = (float*)w;            w += NN * 4;
    float*    bc      = (float*)w;            w += NH * 4;
    _Float16* Wct     = (_Float16*)w;         w += NF * NH * 2;
    _Float16* Wt1     = (_Float16*)w;         w += NH * NH * 2;
    _Float16* Wt2     = (_Float16*)w;         w += NH * NH * 2;
    int*      csr_src = (int*)w;              w += NE * 4;
    int*      tmp     = (int*)w;              w += (size_t)NBUCK * CAP * 4;
    __half*   Bh      = (__half*)w;           w += (size_t)NN * NH * 2;   // hws
    __half*   H16     = (__half*)w;                                      // h

    // --- CSR build (once per call) ---
    hipMemsetAsync(bcnt, 0, 256 * 4, stream);
    part_bucket2<<<(NE + CHA - 1) / CHA, 256, 0, stream>>>(src, dst, bcnt, tmp, NE);
    bucket_finalize<<<NBUCK, 256, 0, stream>>>(bcnt, tmp, rowptr, dsq, csr_src);

    // --- weight prep (merged): fold embed into layer-0, fp16-transpose all ---
    prep_w<<<64, 256, 0, stream>>>(W_emb, b_emb, Ws, Wct, bc, Wt1, Wt2);

    // --- layer 0 GEMM (fused with embedding) ---
    fuse0_gemm<<<NBLK, 256, 0, stream>>>(x, Wct, bc, dsq, Bh);

    // --- gather -> h ; layer GEMMs ---
    gather_h<<<NN / 4, 256, 0, stream>>>(rowptr, csr_src, Bh, dsq, bs, H16);
    layer_gemm<<<NBLK, 256, 0, stream>>>(H16, Wt1, dsq, Bh);
    gather_h<<<NN / 4, 256, 0, stream>>>(rowptr, csr_src, Bh, dsq, bs + NH, H16);
    layer_gemm<<<NBLK, 256, 0, stream>>>(H16, Wt2, dsq, Bh);
    // --- final gather ---
    gather_out<<<NN / 4, 256, 0, stream>>>(rowptr, csr_src, Bh, dsq,
                                           bs + 2 * NH, out);
}

// Round 17
// 265.204 us; speedup vs baseline: 1.0195x; 1.0195x over previous
//
#include <hip/hip_runtime.h>
#include <hip/hip_fp16.h>
#include <math.h>

#define NN 100000
#define NE 1600000
#define NF 128
#define NH 64
#define NBUCK 196     // ceil(NN / 512)
#define CHA 8192      // edges per block in partition pass
#define CAP 10240     // per-bucket capacity (mean 8163, +23 sigma)
#define NBLK 1563     // ceil(NN / 64) for MFMA GEMMs

typedef _Float16 f16x8 __attribute__((ext_vector_type(8)));
typedef float f32x4 __attribute__((ext_vector_type(4)));

// Pass A: partition edges into 512-node dst-buckets (fixed-capacity regions).
// dst chunk cached in LDS so it is read from global only once.
__global__ __launch_bounds__(256) void part_bucket2(const int* __restrict__ src,
                                                    const int* __restrict__ dst,
                                                    int* __restrict__ bcnt,
                                                    int* __restrict__ tmp, int E) {
    __shared__ int hist[NBUCK];
    __shared__ int base[NBUCK];
    __shared__ int dbuf[CHA];    // 32 KB
    int t = threadIdx.x;
    int e0 = blockIdx.x * CHA;
    int n = min(CHA, E - e0);
    if (t < NBUCK) hist[t] = 0;
    __syncthreads();
    for (int i = t; i < n; i += 256) {
        int d = dst[e0 + i];
        dbuf[i] = d;
        atomicAdd(&hist[d >> 9], 1);
    }
    __syncthreads();
    if (t < NBUCK) {
        int h = hist[t];
        base[t] = h ? atomicAdd(&bcnt[t], h) : 0;
        hist[t] = 0;
    }
    __syncthreads();
    for (int i = t; i < n; i += 256) {
        int d = dbuf[i];
        int b = d >> 9;
        int r = atomicAdd(&hist[b], 1);
        tmp[b * CAP + base[b] + r] = ((d & 511) << 17) | src[e0 + i];
    }
}

// Pass B: one block per bucket. Re-derives its CSR base from bcnt (local scan),
// stages entries in LDS, per-node degree histogram (-> rowptr, dsq), LDS scan,
// LDS-cursor scatter into csr_src.
__global__ __launch_bounds__(256) void bucket_finalize(const int* __restrict__ bcnt,
                                                       const int* __restrict__ tmp,
                                                       int* __restrict__ rowptr,
                                                       float* __restrict__ dsq,
                                                       int* __restrict__ csr_src) {
    __shared__ int ebuf[CAP];   // 40 KB
    __shared__ int hcnt[512];
    __shared__ int hoff[512];
    __shared__ int s[256];
    int b = blockIdx.x, t = threadIdx.x;

    // local exclusive scan of bcnt -> this bucket's CSR base
    s[t] = (t < NBUCK) ? bcnt[t] : 0;
    __syncthreads();
    for (int off = 1; off < 256; off <<= 1) {
        int v = (t >= off) ? s[t - off] : 0;
        __syncthreads();
        s[t] += v;
        __syncthreads();
    }
    int base = (b == 0) ? 0 : s[b - 1];
    int cb = bcnt[b];
    if (b == 0 && t == 0) rowptr[NN] = NE;
    __syncthreads();

    const int* tsrc = tmp + b * CAP;
    for (int i = t; i < cb; i += 256) ebuf[i] = tsrc[i];
    hcnt[t] = 0;
    hcnt[t + 256] = 0;
    __syncthreads();
    for (int i = t; i < cb; i += 256) atomicAdd(&hcnt[ebuf[i] >> 17], 1);
    __syncthreads();
    int c0 = hcnt[2 * t], c1 = hcnt[2 * t + 1];
    s[t] = c0 + c1;
    __syncthreads();
    for (int off = 1; off < 256; off <<= 1) {
        int v = (t >= off) ? s[t - off] : 0;
        __syncthreads();
        s[t] += v;
        __syncthreads();
    }
    int pb = (t == 0) ? 0 : s[t - 1];
    hoff[2 * t] = pb;
    hoff[2 * t + 1] = pb + c0;
    __syncthreads();
    int nodelo = b << 9;
    int nnodes = min(512, NN - nodelo);
    for (int i = t; i < nnodes; i += 256) {
        rowptr[nodelo + i] = base + hoff[i];
        dsq[nodelo + i] = rsqrtf((float)hcnt[i] + 1.0f);
    }
    __syncthreads();
    for (int i = t; i < cb; i += 256) {
        int e = ebuf[i];
        int dlow = e >> 17;
        int p = atomicAdd(&hoff[dlow], 1);
        csr_src[base + p] = e & 0x1FFFF;
    }
}

// merged weight prep. blocks 0-31: Wct=(We@W0)^T fp16 + bc; 32-47: Wt1; 48-63: Wt2.
__global__ __launch_bounds__(256) void prep_w(const float* __restrict__ We,
                                              const float* __restrict__ be,
                                              const float* __restrict__ Ws,
                                              _Float16* __restrict__ Wct,
                                              float* __restrict__ bc,
                                              _Float16* __restrict__ Wt1,
                                              _Float16* __restrict__ Wt2) {
    int bb = blockIdx.x;
    int t = threadIdx.x;
    if (bb < 32) {
        __shared__ float w0[NH * NH];
        for (int i = t; i < NH * NH; i += 256) w0[i] = Ws[i];
        __syncthreads();
        int row = bb * 4 + (t >> 6);  // k index 0..127
        int col = t & 63;
        float a = 0.f;
#pragma unroll 8
        for (int k = 0; k < NH; ++k) a += We[row * NH + k] * w0[k * NH + col];
        Wct[col * NF + row] = (_Float16)a;
        if (bb == 0 && t < NH) {
            float s = 0.f;
            for (int k = 0; k < NH; ++k) s += be[k] * w0[k * NH + t];
            bc[t] = s;
        }
    } else {
        int which = (bb - 32) >> 4;          // 0 -> Wt1, 1 -> Wt2
        int i = ((bb - 32) & 15) * 256 + t;  // 0..4095
        int k = i >> 6, c = i & 63;
        const float* W = Ws + (which + 1) * NH * NH;
        _Float16* Wt = which ? Wt2 : Wt1;
        Wt[c * NH + k] = (_Float16)W[i];
    }
}

// hws0 = (x @ Wc + bc) * dsq[row], fp16 out. MFMA 16x16x32_f16, 64 rows/block.
__global__ __launch_bounds__(256) void fuse0_gemm(const float* __restrict__ x,
                                                  const _Float16* __restrict__ Wct,
                                                  const float* __restrict__ bc,
                                                  const float* __restrict__ dsq,
                                                  __half* __restrict__ hws) {
    __shared__ _Float16 sh[64 * NF];  // 16 KB, 256B rows, XOR-swizzled
    int t = threadIdx.x;
    int lane = t & 63;
    int w = t >> 6;
    int row0 = blockIdx.x * 64;

    f16x8 bf[4][4];
#pragma unroll
    for (int ct = 0; ct < 4; ++ct)
#pragma unroll
        for (int ks = 0; ks < 4; ++ks) {
            int col = ct * 16 + (lane & 15);
            int k = ks * 32 + (lane >> 4) * 8;
            bf[ct][ks] = *(const f16x8*)(Wct + col * NF + k);
        }

    const float4* xs = (const float4*)x;
#pragma unroll
    for (int i = 0; i < 8; ++i) {
        int f = t + i * 256;
        int r = f >> 5;
        int c4 = f & 31;
        int row = min(row0 + r, NN - 1);
        float4 v = xs[(size_t)row * 32 + c4];
        __half2 h0 = __floats2half2_rn(v.x, v.y);
        __half2 h1 = __floats2half2_rn(v.z, v.w);
        uint2 u;
        u.x = *(unsigned*)&h0;
        u.y = *(unsigned*)&h1;
        int byte = (r * 256 + c4 * 8) ^ ((r & 7) << 4);
        *(uint2*)((char*)sh + byte) = u;
    }
    __syncthreads();

    f32x4 acc[4] = {{0.f, 0.f, 0.f, 0.f}, {0.f, 0.f, 0.f, 0.f},
                    {0.f, 0.f, 0.f, 0.f}, {0.f, 0.f, 0.f, 0.f}};
    int ar = w * 16 + (lane & 15);
    int ak = (lane >> 4) * 8;
#pragma unroll
    for (int ks = 0; ks < 4; ++ks) {
        int byte = (ar * 256 + (ks * 32 + ak) * 2) ^ ((ar & 7) << 4);
        f16x8 af = *(const f16x8*)((const char*)sh + byte);
#pragma unroll
        for (int ct = 0; ct < 4; ++ct)
            acc[ct] = __builtin_amdgcn_mfma_f32_16x16x32_f16(af, bf[ct][ks], acc[ct], 0, 0, 0);
    }
#pragma unroll
    for (int ct = 0; ct < 4; ++ct) {
        int col = ct * 16 + (lane & 15);
        float bcv = bc[col];
#pragma unroll
        for (int r2 = 0; r2 < 4; ++r2) {
            int row = row0 + w * 16 + (lane >> 4) * 4 + r2;
            if (row < NN)
                hws[(size_t)row * NH + col] = __float2half((acc[ct][r2] + bcv) * dsq[row]);
        }
    }
}

// hws = (h @ W) * dsq[row], fp16 in/out. MFMA, K=64, 64 rows/block.
__global__ __launch_bounds__(256) void layer_gemm(const __half* __restrict__ h,
                                                  const _Float16* __restrict__ Wt,
                                                  const float* __restrict__ dsq,
                                                  __half* __restrict__ hws) {
    __shared__ _Float16 sh[64 * NH];  // 8 KB, 128B rows, XOR-swizzled
    int t = threadIdx.x;
    int lane = t & 63;
    int w = t >> 6;
    int row0 = blockIdx.x * 64;

    f16x8 bf[4][2];
#pragma unroll
    for (int ct = 0; ct < 4; ++ct)
#pragma unroll
        for (int ks = 0; ks < 2; ++ks) {
            int col = ct * 16 + (lane & 15);
            int k = ks * 32 + (lane >> 4) * 8;
            bf[ct][ks] = *(const f16x8*)(Wt + col * NH + k);
        }

#pragma unroll
    for (int i = 0; i < 2; ++i) {
        int u = t + i * 256;
        int r = u >> 3;
        int c8 = u & 7;
        int row = min(row0 + r, NN - 1);
        uint4 v = *(const uint4*)(h + (size_t)row * NH + c8 * 8);
        int byte = (r * 128 + c8 * 16) ^ ((r & 7) << 4);
        *(uint4*)((char*)sh + byte) = v;
    }
    __syncthreads();

    f32x4 acc[4] = {{0.f, 0.f, 0.f, 0.f}, {0.f, 0.f, 0.f, 0.f},
                    {0.f, 0.f, 0.f, 0.f}, {0.f, 0.f, 0.f, 0.f}};
    int ar = w * 16 + (lane & 15);
    int ak = (lane >> 4) * 8;
#pragma unroll
    for (int ks = 0; ks < 2; ++ks) {
        int byte = (ar * 128 + (ks * 32 + ak) * 2) ^ ((ar & 7) << 4);
        f16x8 af = *(const f16x8*)((const char*)sh + byte);
#pragma unroll
        for (int ct = 0; ct < 4; ++ct)
            acc[ct] = __builtin_amdgcn_mfma_f32_16x16x32_f16(af, bf[ct][ks], acc[ct], 0, 0, 0);
    }
#pragma unroll
    for (int ct = 0; ct < 4; ++ct) {
        int col = ct * 16 + (lane & 15);
#pragma unroll
        for (int r2 = 0; r2 < 4; ++r2) {
            int row = row0 + w * 16 + (lane >> 4) * 4 + r2;
            if (row < NN)
                hws[(size_t)row * NH + col] = __float2half(acc[ct][r2] * dsq[row]);
        }
    }
}

// Gather core (R13/R15-proven): wave per node, 4 groups of 16 lanes (4 feats/
// lane, 8B loads). Edge indices: one coalesced read + shfl broadcast.
// Branchless masked super-steps of 16 edges (clamp index + x{0,1} mask).
#define ADDROWM(sidx, m)                                                     \
    {                                                                        \
        uint2 rv = *(const uint2*)(hws_in + (size_t)(sidx) * NH + fl);       \
        float2 f0 = __half22float2(*(const __half2*)&rv.x);                  \
        float2 f1 = __half22float2(*(const __half2*)&rv.y);                  \
        a0 += f0.x * (m); a1 += f0.y * (m);                                  \
        a2 += f1.x * (m); a3 += f1.y * (m);                                  \
    }

#define GATHER_BODY                                                          \
    int t = threadIdx.x;                                                     \
    int node = blockIdx.x * 4 + (t >> 6);                                    \
    int lane = t & 63;                                                       \
    int g = lane >> 4;            /* edge slot 0..3 */                       \
    int fl = (lane & 15) << 2;    /* feature base, 4 feats */                \
    int beg = rowptr[node], end = rowptr[node + 1];                          \
    int deg = end - beg;                                                     \
    float a0 = 0.f, a1 = 0.f, a2 = 0.f, a3 = 0.f;                            \
    if (g == 0) ADDROWM(node, 1.f);                                          \
    int idxl = csr_src[min(beg + lane, NE - 1)];                             \
    {                                                                        \
        int degc = min(deg, 64);                                             \
        int nsup = (degc + 15) >> 4;                                         \
        for (int sup = 0; sup < nsup; ++sup) {                               \
            int eb = sup * 16 + g;                                           \
            _Pragma("unroll")                                                \
            for (int q = 0; q < 4; ++q) {                                    \
                int e = eb + q * 4;                                          \
                int s_ = __shfl(idxl, min(e, degc - 1));                     \
                float m = (e < degc) ? 1.f : 0.f;                            \
                ADDROWM(s_, m);                                              \
            }                                                                \
        }                                                                    \
    }                                                                        \
    for (int jb = beg + 64; jb < end; jb += 64) {  /* deg>64 fallback */     \
        int remc = min(end - jb, 64);                                        \
        int idx2 = csr_src[min(jb + lane, NE - 1)];                          \
        int nsup = (remc + 15) >> 4;                                         \
        for (int sup = 0; sup < nsup; ++sup) {                               \
            int eb = sup * 16 + g;                                           \
            _Pragma("unroll")                                                \
            for (int q = 0; q < 4; ++q) {                                    \
                int e = eb + q * 4;                                          \
                int s_ = __shfl(idx2, min(e, remc - 1));                     \
                float m = (e < remc) ? 1.f : 0.f;                            \
                ADDROWM(s_, m);                                              \
            }                                                                \
        }                                                                    \
    }                                                                        \
    a0 += __shfl_xor(a0, 16); a1 += __shfl_xor(a1, 16);                      \
    a2 += __shfl_xor(a2, 16); a3 += __shfl_xor(a3, 16);                      \
    a0 += __shfl_xor(a0, 32); a1 += __shfl_xor(a1, 32);                      \
    a2 += __shfl_xor(a2, 32); a3 += __shfl_xor(a3, 32);

// h = relu(dsq*(agg+self)+b), fp16 out (feeds layer_gemm)
__global__ __launch_bounds__(256) void gather_h(const int* __restrict__ rowptr,
                                                const int* __restrict__ csr_src,
                                                const __half* __restrict__ hws_in,
                                                const float* __restrict__ dsq,
                                                const float* __restrict__ b,
                                                __half* __restrict__ hout) {
    GATHER_BODY
    if (lane < 16) {
        float ds = dsq[node];
        float4 b0 = *(const float4*)(b + fl);
        __half2 o0 = __floats2half2_rn(fmaxf(ds * a0 + b0.x, 0.f),
                                       fmaxf(ds * a1 + b0.y, 0.f));
        __half2 o1 = __floats2half2_rn(fmaxf(ds * a2 + b0.z, 0.f),
                                       fmaxf(ds * a3 + b0.w, 0.f));
        uint2 u;
        u.x = *(unsigned*)&o0;
        u.y = *(unsigned*)&o1;
        *(uint2*)(hout + (size_t)node * NH + fl) = u;
    }
}

// final: out = relu(dsq*(agg+self)+b), fp32
__global__ __launch_bounds__(256) void gather_out(const int* __restrict__ rowptr,
                                                  const int* __restrict__ csr_src,
                                                  const __half* __restrict__ hws_in,
                                                  const float* __restrict__ dsq,
                                                  const float* __restrict__ b,
                                                  float* __restrict__ outbuf) {
    GATHER_BODY
    if (lane < 16) {
        float ds = dsq[node];
        float4 b0 = *(const float4*)(b + fl);
        float4 o;
        o.x = fmaxf(ds * a0 + b0.x, 0.f);
        o.y = fmaxf(ds * a1 + b0.y, 0.f);
        o.z = fmaxf(ds * a2 + b0.z, 0.f);
        o.w = fmaxf(ds * a3 + b0.w, 0.f);
        *(float4*)(outbuf + (size_t)node * NH + fl) = o;
    }
}

extern "C" void kernel_launch(void* const* d_in, const int* in_sizes, int n_in,
                              void* d_out, int out_size, void* d_ws, size_t ws_size,
                              hipStream_t stream) {
    const float* x     = (const float*)d_in[0];
    const int*   ei    = (const int*)d_in[1];
    const float* W_emb = (const float*)d_in[2];
    const float* b_emb = (const float*)d_in[3];
    const float* Ws    = (const float*)d_in[4];
    const float* bs    = (const float*)d_in[5];
    float* out = (float*)d_out;

    const int* src = ei;
    const int* dst = ei + NE;

    char* w = (char*)d_ws;
    int*      bcnt    = (int*)w;              w += 256 * 4;
    int*      rowptr  = (int*)w;              w += (NN + 1) * 4;
    float*    dsq     = (float*)w;            w += NN * 4;
    float*    bc      = (float*)w;            w += NH * 4;
    _Float16* Wct     = (_Float16*)w;         w += NF * NH * 2;
    _Float16* Wt1     = (_Float16*)w;         w += NH * NH * 2;
    _Float16* Wt2     = (_Float16*)w;         w += NH * NH * 2;
    int*      csr_src = (int*)w;              w += NE * 4;
    int*      tmp     = (int*)w;              w += (size_t)NBUCK * CAP * 4;
    __half*   Bh      = (__half*)w;           w += (size_t)NN * NH * 2;   // hws
    __half*   H16     = (__half*)w;                                      // h

    // --- CSR build (once per call) ---
    hipMemsetAsync(bcnt, 0, 256 * 4, stream);
    part_bucket2<<<(NE + CHA - 1) / CHA, 256, 0, stream>>>(src, dst, bcnt, tmp, NE);
    bucket_finalize<<<NBUCK, 256, 0, stream>>>(bcnt, tmp, rowptr, dsq, csr_src);

    // --- weight prep (merged): fold embed into layer-0, fp16-transpose all ---
    prep_w<<<64, 256, 0, stream>>>(W_emb, b_emb, Ws, Wct, bc, Wt1, Wt2);

    // --- layer 0 GEMM (fused with embedding) ---
    fuse0_gemm<<<NBLK, 256, 0, stream>>>(x, Wct, bc, dsq, Bh);

    // --- gather -> h ; layer GEMMs ---
    gather_h<<<NN / 4, 256, 0, stream>>>(rowptr, csr_src, Bh, dsq, bs, H16);
    layer_gemm<<<NBLK, 256, 0, stream>>>(H16, Wt1, dsq, Bh);
    gather_h<<<NN / 4, 256, 0, stream>>>(rowptr, csr_src, Bh, dsq, bs + NH, H16);
    layer_gemm<<<NBLK, 256, 0, stream>>>(H16, Wt2, dsq, Bh);
    // --- final gather ---
    gather_out<<<NN / 4, 256, 0, stream>>>(rowptr, csr_src, Bh, dsq,
                                           bs + 2 * NH, out);
}